// Round 3
// baseline (143.023 us; speedup 1.0000x reference)
//
#include <hip/hip_runtime.h>

#define NEG_INF (-__builtin_inff())

// Guaranteed 3-input max (VOP3, all-VGPR). Also pins operands into arch VGPRs,
// defeating the compiler's AGPR-banking of accumulators seen in rounds 0/2.
static __device__ __forceinline__ float max3f(float a, float b, float c) {
    float d;
    asm("v_max3_f32 %0, %1, %2, %3" : "=v"(d) : "v"(a), "v"(b), "v"(c));
    return d;
}

// Each thread: 2 output channels x 8 consecutive w pixels at one (n,h).
// acc[2][8]=16 floats + xv[12] + temps fits arch VGPRs -> no accvgpr shuttles.
// Weights scalar (readfirstlane'd co base -> s_load through K$, off VALU pipe).
// Block = 256 threads = 4 co-quarters x 64 w-groups (one full row).
// Grid = N*H = 4096 blocks.
__global__ __launch_bounds__(256, 4) void dil2d_kernel(const float* __restrict__ x,
                                                       const float* __restrict__ w,
                                                       float* __restrict__ out) {
    const int Ci = 4, H = 512, W = 512;

    const int tid = threadIdx.x;
    const int wg  = tid & 63;            // w-group 0..63
    const int w0  = wg << 3;             // 0..504
    const int co0 = __builtin_amdgcn_readfirstlane((tid >> 6) << 1);  // 0,2,4,6 (SGPR)
    const int b   = blockIdx.x;
    const int n   = b >> 9;              // / 512
    const int h   = b & 511;

    float acc[2][8];
#pragma unroll
    for (int cs = 0; cs < 2; ++cs)
#pragma unroll
        for (int j = 0; j < 8; ++j) acc[cs][j] = NEG_INF;

    const float* xn = x + n * (Ci * H * W);

    const bool lo_edge = (w0 == 0);
    const bool hi_edge = (w0 == 504);
    const int  off_lo  = lo_edge ? 0   : (w0 - 4);   // 16B aligned
    const int  off_hi  = hi_edge ? 504 : (w0 + 8);   // 16B aligned

#pragma unroll
    for (int ci = 0; ci < Ci; ++ci) {
        const float* xc  = xn + ci * (H * W);
        const float* wci = w + (co0 * Ci + ci) * 25;   // scalar address
#pragma unroll
        for (int kh = 0; kh < 5; ++kh) {
            const int r = h + kh - 2;
            if (r < 0 || r >= H) continue;   // wave-uniform; -inf pad == skip row
            const float* xr = xc + r * W;

            // window xv[0..11] = x[r][w0-2 .. w0+9], -inf outside image
            const float4 lo4 = *(const float4*)(xr + off_lo);
            const float4 m0  = *(const float4*)(xr + w0);
            const float4 m1  = *(const float4*)(xr + w0 + 4);
            const float4 hi4 = *(const float4*)(xr + off_hi);

            float xv[12];
            xv[0]  = lo_edge ? NEG_INF : lo4.z;
            xv[1]  = lo_edge ? NEG_INF : lo4.w;
            xv[2]  = m0.x; xv[3] = m0.y; xv[4] = m0.z; xv[5] = m0.w;
            xv[6]  = m1.x; xv[7] = m1.y; xv[8] = m1.z; xv[9] = m1.w;
            xv[10] = hi_edge ? NEG_INF : hi4.x;
            xv[11] = hi_edge ? NEG_INF : hi4.y;

            const float* wk = wci + kh * 5;   // scalar -> s_load, off the VALU pipe
#pragma unroll
            for (int cs = 0; cs < 2; ++cs) {
                const float* wco = wk + cs * (Ci * 25);
                const float wv0 = wco[0], wv1 = wco[1], wv2 = wco[2],
                            wv3 = wco[3], wv4 = wco[4];
#pragma unroll
                for (int j = 0; j < 8; ++j) {
                    const float t0 = xv[j]     + wv0;
                    const float t1 = xv[j + 1] + wv1;
                    const float t2 = xv[j + 2] + wv2;
                    const float t3 = xv[j + 3] + wv3;
                    const float t4 = xv[j + 4] + wv4;
                    float m = acc[cs][j];
                    m = max3f(m, t0, t1);
                    m = max3f(m, t2, t3);
                    m = fmaxf(m, t4);
                    acc[cs][j] = m;
                }
            }
        }
    }

    float* on = out + n * (8 * H * W) + co0 * (H * W) + h * W + w0;
#pragma unroll
    for (int cs = 0; cs < 2; ++cs) {
        float* o = on + cs * (H * W);
        *(float4*)(o)     = make_float4(acc[cs][0], acc[cs][1], acc[cs][2], acc[cs][3]);
        *(float4*)(o + 4) = make_float4(acc[cs][4], acc[cs][5], acc[cs][6], acc[cs][7]);
    }
}

extern "C" void kernel_launch(void* const* d_in, const int* in_sizes, int n_in,
                              void* d_out, int out_size, void* d_ws, size_t ws_size,
                              hipStream_t stream) {
    const float* x = (const float*)d_in[0];
    const float* w = (const float*)d_in[1];
    float* out     = (float*)d_out;

    dim3 grid(4096), block(256);
    hipLaunchKernelGGL(dil2d_kernel, grid, block, 0, stream, x, w, out);
}

// Round 5
// 133.713 us; speedup vs baseline: 1.0696x; 1.0696x over previous
//
#include <hip/hip_runtime.h>

#define NEG_INF (-__builtin_inff())

// Guaranteed 3-input max (VOP3, all-VGPR operands).
static __device__ __forceinline__ float max3f(float a, float b, float c) {
    float d;
    asm("v_max3_f32 %0, %1, %2, %3" : "=v"(d) : "v"(a), "v"(b), "v"(c));
    return d;
}

// window xv[0..11] = xr[w0-2 .. w0+9], -inf outside [0,512)
static __device__ __forceinline__ void load_win(const float* __restrict__ xr,
                                                int w0, int off_lo, int off_hi,
                                                bool lo_edge, bool hi_edge,
                                                float* xv) {
    const float4 lo4 = *(const float4*)(xr + off_lo);
    const float4 m0  = *(const float4*)(xr + w0);
    const float4 m1  = *(const float4*)(xr + w0 + 4);
    const float4 hi4 = *(const float4*)(xr + off_hi);
    xv[0]  = lo_edge ? NEG_INF : lo4.z;
    xv[1]  = lo_edge ? NEG_INF : lo4.w;
    xv[2]  = m0.x; xv[3] = m0.y; xv[4] = m0.z; xv[5] = m0.w;
    xv[6]  = m1.x; xv[7] = m1.y; xv[8] = m1.z; xv[9] = m1.w;
    xv[10] = hi_edge ? NEG_INF : hi4.x;
    xv[11] = hi_edge ? NEG_INF : hi4.y;
}

// Each thread: 4 output channels x 8 consecutive w pixels at one (n,h).
// Block = 256 = 2 rows x 2 co-halves x 64 w-groups (R2 structure, best so far).
// + XCD swizzle: work=(b%8)*256+b/8 -> each XCD owns one n (4MB ~= its L2),
//   neighbor blocks share 4/6 input rows in the same L2.
// + interior rows pair (ci,kh) groups: 10 candidates folded with 5 v_max3
//   (core 160 -> 150 issues/px). Edge rows (h<2 | h>509) take generic path.
__global__ __launch_bounds__(256, 4) void dil2d_kernel(const float* __restrict__ x,
                                                       const float* __restrict__ w,
                                                       float* __restrict__ out) {
    const int Ci = 4, H = 512, W = 512;

    const int tid = threadIdx.x;
    const int wg  = tid & 63;            // w-group 0..63
    const int w0  = wg << 3;             // 0..504
    const int coh = (tid >> 6) & 1;      // co half, wave-uniform
    const int rib = tid >> 7;            // row in block, wave-uniform
    const int co0 = __builtin_amdgcn_readfirstlane(coh << 2);   // 0 or 4 (SGPR)
    const int b   = blockIdx.x;
    const int wkid = ((b & 7) << 8) | (b >> 3);   // XCD-aware bijective swizzle
    const int n   = wkid >> 8;
    const int h   = ((wkid & 255) << 1) + rib;

    float acc[4][8];
#pragma unroll
    for (int cs = 0; cs < 4; ++cs)
#pragma unroll
        for (int j = 0; j < 8; ++j) acc[cs][j] = NEG_INF;

    const float* xn = x + n * (Ci * H * W);
    const float* wb = w + co0 * (Ci * 25);        // scalar base for this co-half

    const bool lo_edge = (w0 == 0);
    const bool hi_edge = (w0 == 504);
    const int  off_lo  = lo_edge ? 0   : (w0 - 4);   // 16B aligned
    const int  off_hi  = hi_edge ? 504 : (w0 + 8);   // 16B aligned

    if (h >= 2 && h <= 509) {
        // ---- fast path: all 20 (ci,kh) rows valid; process as 10 pairs ----
#pragma unroll
        for (int p = 0; p < 10; ++p) {
            const int gA = 2 * p, gB = 2 * p + 1;
            const int ciA = gA / 5, khA = gA % 5;
            const int ciB = gB / 5, khB = gB % 5;

            float xa[12], xb[12];
            load_win(xn + ciA * (H * W) + (h + khA - 2) * W,
                     w0, off_lo, off_hi, lo_edge, hi_edge, xa);
            load_win(xn + ciB * (H * W) + (h + khB - 2) * W,
                     w0, off_lo, off_hi, lo_edge, hi_edge, xb);

            const float* wA = wb + ciA * 25 + khA * 5;   // scalar -> s_load
            const float* wB = wb + ciB * 25 + khB * 5;
#pragma unroll
            for (int cs = 0; cs < 4; ++cs) {
                const float wa0 = wA[cs*100+0], wa1 = wA[cs*100+1], wa2 = wA[cs*100+2],
                            wa3 = wA[cs*100+3], wa4 = wA[cs*100+4];
                const float wb0 = wB[cs*100+0], wb1 = wB[cs*100+1], wb2 = wB[cs*100+2],
                            wb3 = wB[cs*100+3], wb4 = wB[cs*100+4];
#pragma unroll
                for (int j = 0; j < 8; ++j) {
                    const float a0 = xa[j]     + wa0;
                    const float a1 = xa[j + 1] + wa1;
                    const float a2 = xa[j + 2] + wa2;
                    const float a3 = xa[j + 3] + wa3;
                    const float a4 = xa[j + 4] + wa4;
                    const float b0 = xb[j]     + wb0;
                    const float b1 = xb[j + 1] + wb1;
                    const float b2 = xb[j + 2] + wb2;
                    const float b3 = xb[j + 3] + wb3;
                    const float b4 = xb[j + 4] + wb4;
                    float m = acc[cs][j];
                    m = max3f(m, a0, a1);
                    m = max3f(m, a2, a3);
                    m = max3f(m, a4, b0);
                    m = max3f(m, b1, b2);
                    m = max3f(m, b3, b4);
                    acc[cs][j] = m;
                }
            }
        }
    } else {
        // ---- edge rows (h in {0,1,510,511}): generic path ----
        for (int ci = 0; ci < Ci; ++ci) {
            for (int kh = 0; kh < 5; ++kh) {
                const int r = h + kh - 2;
                if (r < 0 || r >= H) continue;   // wave-uniform
                float xv[12];
                load_win(xn + ci * (H * W) + r * W,
                         w0, off_lo, off_hi, lo_edge, hi_edge, xv);
                const float* wk = wb + ci * 25 + kh * 5;
#pragma unroll
                for (int cs = 0; cs < 4; ++cs) {
                    const float wv0 = wk[cs*100+0], wv1 = wk[cs*100+1], wv2 = wk[cs*100+2],
                                wv3 = wk[cs*100+3], wv4 = wk[cs*100+4];
#pragma unroll
                    for (int j = 0; j < 8; ++j) {
                        const float t0 = xv[j]     + wv0;
                        const float t1 = xv[j + 1] + wv1;
                        const float t2 = xv[j + 2] + wv2;
                        const float t3 = xv[j + 3] + wv3;
                        const float t4 = xv[j + 4] + wv4;
                        float m = acc[cs][j];
                        m = max3f(m, t0, t1);
                        m = max3f(m, t2, t3);
                        m = fmaxf(m, t4);
                        acc[cs][j] = m;
                    }
                }
            }
        }
    }

    float* on = out + n * (8 * H * W) + co0 * (H * W) + h * W + w0;
#pragma unroll
    for (int cs = 0; cs < 4; ++cs) {
        float* o = on + cs * (H * W);
        *(float4*)(o)     = make_float4(acc[cs][0], acc[cs][1], acc[cs][2], acc[cs][3]);
        *(float4*)(o + 4) = make_float4(acc[cs][4], acc[cs][5], acc[cs][6], acc[cs][7]);
    }
}

extern "C" void kernel_launch(void* const* d_in, const int* in_sizes, int n_in,
                              void* d_out, int out_size, void* d_ws, size_t ws_size,
                              hipStream_t stream) {
    const float* x = (const float*)d_in[0];
    const float* w = (const float*)d_in[1];
    float* out     = (float*)d_out;

    dim3 grid(2048), block(256);
    hipLaunchKernelGGL(dil2d_kernel, grid, block, 0, stream, x, w, out);
}